// Round 7
// baseline (516.937 us; speedup 1.0000x reference)
//
#include <hip/hip_runtime.h>
#include <hip/hip_bf16.h>
#include <math.h>

typedef _Float16 f16;
typedef __attribute__((ext_vector_type(8))) _Float16 f16x8;
typedef __attribute__((ext_vector_type(4))) _Float16 f16x4;
typedef __attribute__((ext_vector_type(4))) float f32x4;

namespace {
constexpr int B = 4, L = 2048, D = 512, NH = 8, DH = 64;
constexpr int HALF = 1024;                 // K-columns per attention block (split-L x2)
}

// ---- E cast: fp32 -> fp16 ----
__global__ __launch_bounds__(256)
void ecast_kernel(const float* __restrict__ E, f16* __restrict__ Ef) {
    int i4 = (blockIdx.x * 256 + threadIdx.x) * 4;
    float4 x = *(const float4*)(E + i4);
    *(f16x4*)(Ef + i4) = (f16x4){(f16)x.x, (f16)x.y, (f16)x.z, (f16)x.w};
}

// ---- W transpose+cast: W[k][n] fp32 -> Wt[sel][n][k] fp16 ----
__global__ __launch_bounds__(256)
void wtrans_kernel(const float* __restrict__ Wq, const float* __restrict__ Wk,
                   const float* __restrict__ Wv, f16* __restrict__ Wt) {
    __shared__ f16 Ws[64 * 65];
    const int sel = blockIdx.z;
    const float* W = (sel == 0) ? Wq : (sel == 1) ? Wk : Wv;
    f16* Wo = Wt + (size_t)sel * D * D;
    const int k0 = blockIdx.x * 64, n0 = blockIdx.y * 64;
    const int t = threadIdx.x;
#pragma unroll
    for (int i = 0; i < 16; ++i) {
        int idx = 256 * i + t;
        int r = idx >> 6, c = idx & 63;
        Ws[r * 65 + c] = (f16)W[(size_t)(k0 + r) * D + n0 + c];
    }
    __syncthreads();
    const int c = t >> 2, kseg = t & 3;
    f16x8 r0, r1;
#pragma unroll
    for (int j = 0; j < 8; ++j) r0[j] = Ws[(kseg * 16 + j) * 65 + c];
#pragma unroll
    for (int j = 0; j < 8; ++j) r1[j] = Ws[(kseg * 16 + 8 + j) * 65 + c];
    f16* o = Wo + (size_t)(n0 + c) * D + k0 + kseg * 16;
    *(f16x8*)o = r0;
    *(f16x8*)(o + 8) = r1;
}

// ---- fused projections: C = X(fp32) . W, fp16 MFMA ----
__global__ __launch_bounds__(256, 4)
void proj_gemm(const float* __restrict__ q, const float* __restrict__ k,
               const float* __restrict__ v, const f16* __restrict__ Wt,
               f16* __restrict__ Qf, f16* __restrict__ Kf, f16* __restrict__ Vtf) {
    __shared__ f16 As[128 * 72];
    __shared__ f16 Bs[64 * 72];
    const int bx = blockIdx.x, by = blockIdx.y;
    const int sel = by >> 3, h = by & 7;
    const int m0 = bx * 128;
    const float* X = (sel == 0) ? q : (sel == 1) ? k : v;
    const f16* Bt = Wt + (size_t)sel * D * D + (size_t)h * 64 * D;
    const int t = threadIdx.x, wid = t >> 6, lane = t & 63;
    const int quad = lane >> 4, col = lane & 15;
    const int mw = wid * 32;

    f32x4 acc[2][4];
#pragma unroll
    for (int i = 0; i < 2; ++i)
#pragma unroll
        for (int j = 0; j < 4; ++j) acc[i][j] = (f32x4){0.f, 0.f, 0.f, 0.f};

    float4 xa[8];
    f16x8 breg[2];
    auto loadG = [&](int k0) {
#pragma unroll
        for (int i = 0; i < 8; ++i) {
            int idx = 256 * i + t;
            int r = idx >> 4, c4 = idx & 15;
            xa[i] = *(const float4*)(X + (size_t)(m0 + r) * D + k0 + c4 * 4);
        }
#pragma unroll
        for (int i = 0; i < 2; ++i) {
            int idx = 256 * i + t;
            int r = idx >> 3, ch = idx & 7;
            breg[i] = *(const f16x8*)(Bt + (size_t)r * D + k0 + ch * 8);
        }
    };
    auto storeL = [&]() {
#pragma unroll
        for (int i = 0; i < 8; ++i) {
            int idx = 256 * i + t;
            int r = idx >> 4, c4 = idx & 15;
            *(f16x4*)(As + r * 72 + c4 * 4) =
                (f16x4){(f16)xa[i].x, (f16)xa[i].y, (f16)xa[i].z, (f16)xa[i].w};
        }
#pragma unroll
        for (int i = 0; i < 2; ++i) {
            int idx = 256 * i + t;
            int r = idx >> 3, ch = idx & 7;
            *(f16x8*)(Bs + r * 72 + ch * 8) = breg[i];
        }
    };

    loadG(0);
    for (int k0 = 0; k0 < D; k0 += 64) {
        __syncthreads();
        storeL();
        __syncthreads();
        if (k0 + 64 < D) loadG(k0 + 64);
#pragma unroll
        for (int ks = 0; ks < 2; ++ks) {
            f16x8 af[2], bfr[4];
#pragma unroll
            for (int mt = 0; mt < 2; ++mt)
                af[mt] = *(const f16x8*)(As + (mw + mt * 16 + col) * 72 + quad * 8 + ks * 32);
#pragma unroll
            for (int nt = 0; nt < 4; ++nt)
                bfr[nt] = *(const f16x8*)(Bs + (nt * 16 + col) * 72 + quad * 8 + ks * 32);
#pragma unroll
            for (int mt = 0; mt < 2; ++mt)
#pragma unroll
                for (int nt = 0; nt < 4; ++nt)
                    acc[mt][nt] = __builtin_amdgcn_mfma_f32_16x16x32_f16(af[mt], bfr[nt], acc[mt][nt], 0, 0, 0);
        }
    }

    if (sel < 2) {
        f16* Y = (sel == 0) ? Qf : Kf;
#pragma unroll
        for (int mt = 0; mt < 2; ++mt)
#pragma unroll
            for (int nt = 0; nt < 4; ++nt)
#pragma unroll
                for (int reg = 0; reg < 4; ++reg) {
                    int m = m0 + mw + mt * 16 + quad * 4 + reg;
                    int bb = m >> 11, l = m & 2047, d = nt * 16 + col;
                    Y[((size_t)(bb * NH + h) * L + l) * DH + d] = (f16)acc[mt][nt][reg];
                }
    } else {
        __syncthreads();
        f16* Cs = As;
#pragma unroll
        for (int mt = 0; mt < 2; ++mt)
#pragma unroll
            for (int nt = 0; nt < 4; ++nt)
#pragma unroll
                for (int reg = 0; reg < 4; ++reg) {
                    int d = nt * 16 + col;
                    int lc = mw + mt * 16 + quad * 4 + reg;
                    Cs[d * 136 + lc] = (f16)acc[mt][nt][reg];
                }
        __syncthreads();
        const int dd = t >> 2, seg = t & 3;
        const int bb = m0 >> 11, l0 = m0 & 2047;
        f16* Yv = Vtf + ((size_t)(bb * NH + h) * DH + dd) * L + l0 + seg * 32;
#pragma unroll
        for (int j = 0; j < 4; ++j)
            *(f16x8*)(Yv + j * 8) = *(const f16x8*)(Cs + dd * 136 + seg * 32 + j * 8);
    }
}

// ---- flash attention: barrier-free, direct global fragment loads ----
//   rel = c-l; rel<=0: q[l].E[rel+L-1]; rel==1: 0; rel>=2: q[l+1].E[rel-2]
// G[r][jj], jj=cc-r+15, jbaseA=d0+L-16 / jbaseB=d0-17.
// Scatter: source lane pre-selects G[ns]/G[ns+1], one bpermute per (reg,ns).
// Partials (split-L x2): unnormalized O (fp16) + per-row m,s; /8 in combine.
__global__ __launch_bounds__(256)
void attn_kernel(const f16* __restrict__ Qf, const f16* __restrict__ Kf,
                 const f16* __restrict__ Vtf, const f16* __restrict__ Ef,
                 f16* __restrict__ Opart, float* __restrict__ Mpart,
                 float* __restrict__ Spart) {
    __shared__ f16 Pbuf[4][16 * 72];   // wave-private; no cross-wave sharing -> no barriers

    const int t = threadIdx.x, wid = t >> 6, lane = t & 63;
    const int quad = lane >> 4, col = lane & 15;
    const int l0w = blockIdx.x * 64 + wid * 16;
    const int h = blockIdx.y;
    const int bb = blockIdx.z >> 1, half = blockIdx.z & 1;
    const int c0beg = half * HALF, c0end = c0beg + HALF;
    const size_t head = (size_t)(bb * NH + h) * (size_t)(L * DH);
    const f16* qf = Qf + head;
    const f16* kf = Kf + head;
    const f16* vt = Vtf + head;      // [dh][L]
    f16* Pw = Pbuf[wid];

    f16x8 qF[2], qS[2];
    {
        const int m = l0w + col;
        const int mS = min(m + 1, L - 1);   // row L never actually used
#pragma unroll
        for (int ks = 0; ks < 2; ++ks) {
            const int off = quad * 8 + ks * 32;
            qF[ks] = *(const f16x8*)(qf + (size_t)m * DH + off);
            qS[ks] = *(const f16x8*)(qf + (size_t)mS * DH + off);
        }
    }

    f32x4 O[4];
#pragma unroll
    for (int i = 0; i < 4; ++i) O[i] = (f32x4){0.f, 0.f, 0.f, 0.f};
    float mrow[4] = {-1e30f, -1e30f, -1e30f, -1e30f};
    float srow[4] = {0.f, 0.f, 0.f, 0.f};

    for (int c0 = c0beg; c0 < c0end; c0 += 64) {
        const int d0 = c0 - l0w;

        // ---- S = Q K^T : K fragments direct from global (L2-resident) ----
        f32x4 S[4];
#pragma unroll
        for (int ns = 0; ns < 4; ++ns) {
            S[ns] = (f32x4){0.f, 0.f, 0.f, 0.f};
            const size_t kb = (size_t)(c0 + ns * 16 + col) * DH + quad * 8;
#pragma unroll
            for (int ks = 0; ks < 2; ++ks) {
                f16x8 bh = *(const f16x8*)(kf + kb + ks * 32);
                S[ns] = __builtin_amdgcn_mfma_f32_16x16x32_f16(qF[ks], bh, S[ns], 0, 0, 0);
            }
        }

        // ---- Srel: chunked G + select-at-source scatter ----
        const bool doA = (d0 <= 15);
        const bool doB = (d0 >= -61);
#pragma unroll 1
        for (int pass = 0; pass < 2; ++pass) {
            if ((pass == 0 && !doA) || (pass == 1 && !doB)) continue;
            const int jbase = (pass == 0) ? (d0 + L - 16) : (d0 - 17);
            auto calcG = [&](int g) -> f32x4 {
                int er = min(max(jbase + g * 16 + col, 0), L - 1);
                f32x4 G = (f32x4){0.f, 0.f, 0.f, 0.f};
                const size_t eb = (size_t)er * DH + quad * 8;
#pragma unroll
                for (int ks = 0; ks < 2; ++ks) {
                    f16x8 e8 = *(const f16x8*)(Ef + eb + ks * 32);
                    G = __builtin_amdgcn_mfma_f32_16x16x32_f16(
                            (pass == 0) ? qF[ks] : qS[ks], e8, G, 0, 0, 0);
                }
                return G;
            };
            f32x4 Ga = calcG(0), Gb;
#pragma unroll
            for (int ns = 0; ns < 4; ++ns) {
                Gb = calcG(ns + 1);
#pragma unroll
                for (int reg = 0; reg < 4; ++reg) {
                    const int r = quad * 4 + reg;
                    // this lane, as SOURCE (own col), pre-selects which G-block
                    const float tmp = (col >= 15 - r) ? Ga[reg] : Gb[reg];
                    const int src = quad * 16 + ((col - r + 15) & 15);
                    const float val = __shfl(tmp, src, 64);
                    const int rel = d0 + ns * 16 + col - r;
                    const bool use = (pass == 0) ? (rel <= 0) : (rel >= 2);
                    if (use) S[ns][reg] += val;
                }
                Ga = Gb;
            }
        }

        // ---- online softmax (16-lane row groups) ----
#pragma unroll
        for (int reg = 0; reg < 4; ++reg) {
            float tm = fmaxf(fmaxf(S[0][reg], S[1][reg]), fmaxf(S[2][reg], S[3][reg]));
#pragma unroll
            for (int msk = 1; msk < 16; msk <<= 1)
                tm = fmaxf(tm, __shfl_xor(tm, msk, 16));
            const float mnew  = fmaxf(mrow[reg], tm);
            const float alpha = __expf(mrow[reg] - mnew);
            float p[4], ps = 0.f;
#pragma unroll
            for (int ns = 0; ns < 4; ++ns) { p[ns] = __expf(S[ns][reg] - mnew); ps += p[ns]; }
#pragma unroll
            for (int msk = 1; msk < 16; msk <<= 1)
                ps += __shfl_xor(ps, msk, 16);
            srow[reg] = srow[reg] * alpha + ps;
            mrow[reg] = mnew;
            const int r = quad * 4 + reg;
#pragma unroll
            for (int ns = 0; ns < 4; ++ns) {
                O[ns][reg] *= alpha;
                Pw[r * 72 + ns * 16 + col] = (f16)p[ns];
            }
        }
        // wave-private Pw write->read ordered by lgkmcnt within the wave

        // ---- O += P V : V fragments direct from global ----
        f16x8 pA[2];
        pA[0] = *(const f16x8*)(Pw + col * 72 + quad * 8);
        pA[1] = *(const f16x8*)(Pw + col * 72 + 32 + quad * 8);
#pragma unroll
        for (int ns = 0; ns < 4; ++ns) {
            const size_t vb = (size_t)(ns * 16 + col) * L + c0 + quad * 8;
#pragma unroll
            for (int ks = 0; ks < 2; ++ks) {
                f16x8 v8 = *(const f16x8*)(vt + vb + ks * 32);
                O[ns] = __builtin_amdgcn_mfma_f32_16x16x32_f16(pA[ks], v8, O[ns], 0, 0, 0);
            }
        }
    }

    // ---- partial epilogue: unnormalized O (fp16) + m,s per row ----
#pragma unroll
    for (int reg = 0; reg < 4; ++reg) {
        const int l = l0w + quad * 4 + reg;
        const size_t row = ((size_t)(half * B + bb) * NH + h) * L + l;
        f16* o = Opart + row * DH;
#pragma unroll
        for (int ns = 0; ns < 4; ++ns)
            o[ns * 16 + col] = (f16)O[ns][reg];
        if (col == 0) {
            Mpart[row] = mrow[reg];
            Spart[row] = srow[reg];
        }
    }
}

// ---- combine two split-L partials; applies /(s*8), writes fp32 out ----
__global__ __launch_bounds__(256)
void combine_kernel(const f16* __restrict__ Opart, const float* __restrict__ Mpart,
                    const float* __restrict__ Spart, float* __restrict__ out) {
    const int gid = blockIdx.x * 256 + threadIdx.x;
    const int row = gid >> 3;                           // (bb*NH+h)*L + l
    const int dseg = (gid & 7) * 8;
    const int bb = row >> 14;
    const int rem = row & 16383;
    const int h = rem >> 11, l = rem & 2047;
    const int HSTRIDE = B * NH * L;

    const float m0 = Mpart[row], m1 = Mpart[row + HSTRIDE];
    const float s0 = Spart[row], s1 = Spart[row + HSTRIDE];
    const float m = fmaxf(m0, m1);
    const float e0 = __expf(m0 - m), e1 = __expf(m1 - m);
    const float inv = 1.0f / ((s0 * e0 + s1 * e1) * 8.0f);
    const float w0 = e0 * inv, w1 = e1 * inv;

    f16x8 o0 = *(const f16x8*)(Opart + (size_t)row * DH + dseg);
    f16x8 o1 = *(const f16x8*)(Opart + ((size_t)row + HSTRIDE) * DH + dseg);
    float* o = out + ((size_t)bb * L + l) * D + h * DH + dseg;
    float4 lo, hi;
    lo.x = (float)o0[0] * w0 + (float)o1[0] * w1;
    lo.y = (float)o0[1] * w0 + (float)o1[1] * w1;
    lo.z = (float)o0[2] * w0 + (float)o1[2] * w1;
    lo.w = (float)o0[3] * w0 + (float)o1[3] * w1;
    hi.x = (float)o0[4] * w0 + (float)o1[4] * w1;
    hi.y = (float)o0[5] * w0 + (float)o1[5] * w1;
    hi.z = (float)o0[6] * w0 + (float)o1[6] * w1;
    hi.w = (float)o0[7] * w0 + (float)o1[7] * w1;
    *(float4*)o = lo;
    *(float4*)(o + 4) = hi;
}

extern "C" void kernel_launch(void* const* d_in, const int* in_sizes, int n_in,
                              void* d_out, int out_size, void* d_ws, size_t ws_size,
                              hipStream_t stream) {
    const float* q  = (const float*)d_in[0];
    const float* k  = (const float*)d_in[1];
    const float* v  = (const float*)d_in[2];
    const float* Wq = (const float*)d_in[3];
    const float* Wk = (const float*)d_in[4];
    const float* Wv = (const float*)d_in[5];
    const float* E  = (const float*)d_in[6];
    float* out = (float*)d_out;

    const size_t plane = (size_t)B * NH * L * DH;
    f16* Qf  = (f16*)d_ws;
    f16* Kfp = Qf + plane;
    f16* Vtf = Kfp + plane;
    f16* Wt  = Vtf + plane;
    f16* Ef  = Wt + (size_t)3 * D * D;
    f16* Opart = Ef + (size_t)L * DH;
    float* Mpart = (float*)(Opart + 2 * plane);
    float* Spart = Mpart + (size_t)2 * B * NH * L;

    ecast_kernel<<<L * DH / 1024, 256, 0, stream>>>(E, Ef);
    wtrans_kernel<<<dim3(8, 8, 3), 256, 0, stream>>>(Wq, Wk, Wv, Wt);
    proj_gemm<<<dim3(64, 24), 256, 0, stream>>>(q, k, v, Wt, Qf, Kfp, Vtf);
    attn_kernel<<<dim3(L / 64, NH, B * 2), 256, 0, stream>>>(Qf, Kfp, Vtf, Ef,
                                                             Opart, Mpart, Spart);
    combine_kernel<<<(B * NH * L * DH / 8) / 256, 256, 0, stream>>>(Opart, Mpart, Spart, out);
}

// Round 8
// 395.174 us; speedup vs baseline: 1.3081x; 1.3081x over previous
//
#include <hip/hip_runtime.h>
#include <hip/hip_bf16.h>
#include <math.h>

typedef _Float16 f16;
typedef __attribute__((ext_vector_type(8))) _Float16 f16x8;
typedef __attribute__((ext_vector_type(4))) _Float16 f16x4;
typedef __attribute__((ext_vector_type(4))) float f32x4;

namespace {
constexpr int B = 4, L = 2048, D = 512, NH = 8, DH = 64;
constexpr int HALF = 1024;                 // K-columns per attention block (split-L x2)
}

// ---- E cast: fp32 -> fp16 ----
__global__ __launch_bounds__(256)
void ecast_kernel(const float* __restrict__ E, f16* __restrict__ Ef) {
    int i4 = (blockIdx.x * 256 + threadIdx.x) * 4;
    float4 x = *(const float4*)(E + i4);
    *(f16x4*)(Ef + i4) = (f16x4){(f16)x.x, (f16)x.y, (f16)x.z, (f16)x.w};
}

// ---- W transpose+cast: W[k][n] fp32 -> Wt[sel][n][k] fp16 ----
__global__ __launch_bounds__(256)
void wtrans_kernel(const float* __restrict__ Wq, const float* __restrict__ Wk,
                   const float* __restrict__ Wv, f16* __restrict__ Wt) {
    __shared__ f16 Ws[64 * 65];
    const int sel = blockIdx.z;
    const float* W = (sel == 0) ? Wq : (sel == 1) ? Wk : Wv;
    f16* Wo = Wt + (size_t)sel * D * D;
    const int k0 = blockIdx.x * 64, n0 = blockIdx.y * 64;
    const int t = threadIdx.x;
#pragma unroll
    for (int i = 0; i < 16; ++i) {
        int idx = 256 * i + t;
        int r = idx >> 6, c = idx & 63;
        Ws[r * 65 + c] = (f16)W[(size_t)(k0 + r) * D + n0 + c];
    }
    __syncthreads();
    const int c = t >> 2, kseg = t & 3;
    f16x8 r0, r1;
#pragma unroll
    for (int j = 0; j < 8; ++j) r0[j] = Ws[(kseg * 16 + j) * 65 + c];
#pragma unroll
    for (int j = 0; j < 8; ++j) r1[j] = Ws[(kseg * 16 + 8 + j) * 65 + c];
    f16* o = Wo + (size_t)(n0 + c) * D + k0 + kseg * 16;
    *(f16x8*)o = r0;
    *(f16x8*)(o + 8) = r1;
}

// ---- fused projections: C = X(fp32) . W, fp16 MFMA ----
__global__ __launch_bounds__(256, 4)
void proj_gemm(const float* __restrict__ q, const float* __restrict__ k,
               const float* __restrict__ v, const f16* __restrict__ Wt,
               f16* __restrict__ Qf, f16* __restrict__ Kf, f16* __restrict__ Vtf) {
    __shared__ f16 As[128 * 72];
    __shared__ f16 Bs[64 * 72];
    const int bx = blockIdx.x, by = blockIdx.y;
    const int sel = by >> 3, h = by & 7;
    const int m0 = bx * 128;
    const float* X = (sel == 0) ? q : (sel == 1) ? k : v;
    const f16* Bt = Wt + (size_t)sel * D * D + (size_t)h * 64 * D;
    const int t = threadIdx.x, wid = t >> 6, lane = t & 63;
    const int quad = lane >> 4, col = lane & 15;
    const int mw = wid * 32;

    f32x4 acc[2][4];
#pragma unroll
    for (int i = 0; i < 2; ++i)
#pragma unroll
        for (int j = 0; j < 4; ++j) acc[i][j] = (f32x4){0.f, 0.f, 0.f, 0.f};

    float4 xa[8];
    f16x8 breg[2];
    auto loadG = [&](int k0) {
#pragma unroll
        for (int i = 0; i < 8; ++i) {
            int idx = 256 * i + t;
            int r = idx >> 4, c4 = idx & 15;
            xa[i] = *(const float4*)(X + (size_t)(m0 + r) * D + k0 + c4 * 4);
        }
#pragma unroll
        for (int i = 0; i < 2; ++i) {
            int idx = 256 * i + t;
            int r = idx >> 3, ch = idx & 7;
            breg[i] = *(const f16x8*)(Bt + (size_t)r * D + k0 + ch * 8);
        }
    };
    auto storeL = [&]() {
#pragma unroll
        for (int i = 0; i < 8; ++i) {
            int idx = 256 * i + t;
            int r = idx >> 4, c4 = idx & 15;
            *(f16x4*)(As + r * 72 + c4 * 4) =
                (f16x4){(f16)xa[i].x, (f16)xa[i].y, (f16)xa[i].z, (f16)xa[i].w};
        }
#pragma unroll
        for (int i = 0; i < 2; ++i) {
            int idx = 256 * i + t;
            int r = idx >> 3, ch = idx & 7;
            *(f16x8*)(Bs + r * 72 + ch * 8) = breg[i];
        }
    };

    loadG(0);
    for (int k0 = 0; k0 < D; k0 += 64) {
        __syncthreads();
        storeL();
        __syncthreads();
        if (k0 + 64 < D) loadG(k0 + 64);
#pragma unroll
        for (int ks = 0; ks < 2; ++ks) {
            f16x8 af[2], bfr[4];
#pragma unroll
            for (int mt = 0; mt < 2; ++mt)
                af[mt] = *(const f16x8*)(As + (mw + mt * 16 + col) * 72 + quad * 8 + ks * 32);
#pragma unroll
            for (int nt = 0; nt < 4; ++nt)
                bfr[nt] = *(const f16x8*)(Bs + (nt * 16 + col) * 72 + quad * 8 + ks * 32);
#pragma unroll
            for (int mt = 0; mt < 2; ++mt)
#pragma unroll
                for (int nt = 0; nt < 4; ++nt)
                    acc[mt][nt] = __builtin_amdgcn_mfma_f32_16x16x32_f16(af[mt], bfr[nt], acc[mt][nt], 0, 0, 0);
        }
    }

    if (sel < 2) {
        f16* Y = (sel == 0) ? Qf : Kf;
#pragma unroll
        for (int mt = 0; mt < 2; ++mt)
#pragma unroll
            for (int nt = 0; nt < 4; ++nt)
#pragma unroll
                for (int reg = 0; reg < 4; ++reg) {
                    int m = m0 + mw + mt * 16 + quad * 4 + reg;
                    int bb = m >> 11, l = m & 2047, d = nt * 16 + col;
                    Y[((size_t)(bb * NH + h) * L + l) * DH + d] = (f16)acc[mt][nt][reg];
                }
    } else {
        __syncthreads();
        f16* Cs = As;
#pragma unroll
        for (int mt = 0; mt < 2; ++mt)
#pragma unroll
            for (int nt = 0; nt < 4; ++nt)
#pragma unroll
                for (int reg = 0; reg < 4; ++reg) {
                    int d = nt * 16 + col;
                    int lc = mw + mt * 16 + quad * 4 + reg;
                    Cs[d * 136 + lc] = (f16)acc[mt][nt][reg];
                }
        __syncthreads();
        const int dd = t >> 2, seg = t & 3;
        const int bb = m0 >> 11, l0 = m0 & 2047;
        f16* Yv = Vtf + ((size_t)(bb * NH + h) * DH + dd) * L + l0 + seg * 32;
#pragma unroll
        for (int j = 0; j < 4; ++j)
            *(f16x8*)(Yv + j * 8) = *(const f16x8*)(Cs + dd * 136 + seg * 32 + j * 8);
    }
}

// ---- flash attention: R5 structure (LDS-staged, 2 barriers/tile) + split-L x2 ----
//   rel = c-l; rel<=0: q[l].E[rel+L-1]; rel==1: 0; rel>=2: q[l+1].E[rel-2]
// G[r][jj], jj=cc-r+15, jbaseA=d0+L-16 / jbaseB=d0-17; scatter via intra-quad shfl.
// Row-sum s via ones-column MFMA (accumulates like O with identical alpha).
// Partials: unnormalized O (fp16) + per-row m,s; /8 applied in combine.
__global__ __launch_bounds__(256)
void attn_kernel(const f16* __restrict__ Qf, const f16* __restrict__ Kf,
                 const f16* __restrict__ Vtf, const f16* __restrict__ Ef,
                 f16* __restrict__ Opart, float* __restrict__ Mpart,
                 float* __restrict__ Spart) {
    __shared__ f16 KfS[64 * 72];
    __shared__ f16 VfS[64 * 72];
    __shared__ f16 Pbuf[4][16 * 72];

    const int t = threadIdx.x, wid = t >> 6, lane = t & 63;
    const int quad = lane >> 4, col = lane & 15;
    const int l0w = blockIdx.x * 64 + wid * 16;
    const int h = blockIdx.y;
    const int bb = blockIdx.z >> 1, half = blockIdx.z & 1;
    const int c0beg = half * HALF, c0end = c0beg + HALF;
    const size_t head = (size_t)(bb * NH + h) * (size_t)(L * DH);
    const f16* qf = Qf + head;
    const f16* kf = Kf + head;
    const f16* vt = Vtf + head;      // [dh][L]
    f16* Pw = Pbuf[wid];

    f16x8 qF[2], qS[2];
    {
        const int m = l0w + col;
        const int mS = min(m + 1, L - 1);   // row L never actually used
#pragma unroll
        for (int ks = 0; ks < 2; ++ks) {
            const int off = quad * 8 + ks * 32;
            qF[ks] = *(const f16x8*)(qf + (size_t)m * DH + off);
            qS[ks] = *(const f16x8*)(qf + (size_t)mS * DH + off);
        }
    }

    f16x8 onesf;
#pragma unroll
    for (int j = 0; j < 8; ++j) onesf[j] = (f16)1.0f;

    f16x8 kreg[2], vreg[2];
    auto loadKV = [&](int c0) {
#pragma unroll
        for (int i = 0; i < 2; ++i) {
            int idx = 256 * i + t;
            int r = idx >> 3, ch = idx & 7;
            kreg[i] = *(const f16x8*)(kf + (size_t)(c0 + r) * DH + ch * 8);
            vreg[i] = *(const f16x8*)(vt + (size_t)r * L + c0 + ch * 8);
        }
    };

    f32x4 O[4], Osum;
#pragma unroll
    for (int i = 0; i < 4; ++i) O[i] = (f32x4){0.f, 0.f, 0.f, 0.f};
    Osum = (f32x4){0.f, 0.f, 0.f, 0.f};
    float mrow[4] = {-1e30f, -1e30f, -1e30f, -1e30f};

    loadKV(c0beg);
    for (int c0 = c0beg; c0 < c0end; c0 += 64) {
        __syncthreads();   // all waves done reading previous K/V tile
#pragma unroll
        for (int i = 0; i < 2; ++i) {
            int idx = 256 * i + t;
            int r = idx >> 3, ch = idx & 7;
            *(f16x8*)(KfS + r * 72 + ch * 8) = kreg[i];
            *(f16x8*)(VfS + r * 72 + ch * 8) = vreg[i];
        }
        __syncthreads();
        if (c0 + 64 < c0end) loadKV(c0 + 64);   // in flight across this tile's compute

        const int d0 = c0 - l0w;

        // ---- S = Q K^T (fp16 single pass) ----
        f32x4 S[4];
#pragma unroll
        for (int ns = 0; ns < 4; ++ns) {
            S[ns] = (f32x4){0.f, 0.f, 0.f, 0.f};
#pragma unroll
            for (int ks = 0; ks < 2; ++ks) {
                f16x8 bh = *(const f16x8*)(KfS + (ns * 16 + col) * 72 + quad * 8 + ks * 32);
                S[ns] = __builtin_amdgcn_mfma_f32_16x16x32_f16(qF[ks], bh, S[ns], 0, 0, 0);
            }
        }

        // ---- Srel: G = Q . E-window^T, scatter via intra-quad shuffles ----
        const bool doA = (d0 <= 15);
        const bool doB = (d0 >= -61);
#pragma unroll 1
        for (int pass = 0; pass < 2; ++pass) {
            if ((pass == 0 && !doA) || (pass == 1 && !doB)) continue;
            const int jbase = (pass == 0) ? (d0 + L - 16) : (d0 - 17);
            f32x4 G[5];
#pragma unroll
            for (int g = 0; g < 5; ++g) {
                int er = min(max(jbase + g * 16 + col, 0), L - 1);
                G[g] = (f32x4){0.f, 0.f, 0.f, 0.f};
                const size_t eb = (size_t)er * DH + quad * 8;
#pragma unroll
                for (int ks = 0; ks < 2; ++ks) {
                    f16x8 e8 = *(const f16x8*)(Ef + eb + ks * 32);
                    G[g] = __builtin_amdgcn_mfma_f32_16x16x32_f16(
                               (pass == 0) ? qF[ks] : qS[ks], e8, G[g], 0, 0, 0);
                }
            }
#pragma unroll
            for (int reg = 0; reg < 4; ++reg) {
                const int r  = quad * 4 + reg;
                const int jj = col - r + 15;            // [0,30]
                const int src = quad * 16 + (jj & 15);  // same quad holds row r
#pragma unroll
                for (int ns = 0; ns < 4; ++ns) {
                    float v0 = __shfl(G[ns][reg], src, 64);
                    float v1 = __shfl(G[ns + 1][reg], src, 64);
                    float val = (jj < 16) ? v0 : v1;
                    const int rel = d0 + ns * 16 + col - r;
                    const bool use = (pass == 0) ? (rel <= 0) : (rel >= 2);
                    if (use) S[ns][reg] += val;
                }
            }
        }

        // ---- online softmax (16-lane row groups); row sum deferred to MFMA ----
#pragma unroll
        for (int reg = 0; reg < 4; ++reg) {
            float tm = fmaxf(fmaxf(S[0][reg], S[1][reg]), fmaxf(S[2][reg], S[3][reg]));
#pragma unroll
            for (int msk = 1; msk < 16; msk <<= 1)
                tm = fmaxf(tm, __shfl_xor(tm, msk, 16));
            const float mnew  = fmaxf(mrow[reg], tm);
            const float alpha = __expf(mrow[reg] - mnew);
            mrow[reg] = mnew;
            Osum[reg] *= alpha;
            const int r = quad * 4 + reg;
#pragma unroll
            for (int ns = 0; ns < 4; ++ns) {
                O[ns][reg] *= alpha;
                Pw[r * 72 + ns * 16 + col] = (f16)__expf(S[ns][reg] - mnew);
            }
        }
        // wave-private Pw write->read ordered by lgkmcnt within the wave

        // ---- O += P V ; Osum += P . 1 (row-sum column) ----
        f16x8 pA[2];
        pA[0] = *(const f16x8*)(Pw + col * 72 + quad * 8);
        pA[1] = *(const f16x8*)(Pw + col * 72 + 32 + quad * 8);
#pragma unroll
        for (int ns = 0; ns < 4; ++ns) {
#pragma unroll
            for (int ks = 0; ks < 2; ++ks) {
                f16x8 v8 = *(const f16x8*)(VfS + (ns * 16 + col) * 72 + quad * 8 + ks * 32);
                O[ns] = __builtin_amdgcn_mfma_f32_16x16x32_f16(pA[ks], v8, O[ns], 0, 0, 0);
            }
        }
        Osum = __builtin_amdgcn_mfma_f32_16x16x32_f16(pA[0], onesf, Osum, 0, 0, 0);
        Osum = __builtin_amdgcn_mfma_f32_16x16x32_f16(pA[1], onesf, Osum, 0, 0, 0);
    }

    // ---- partial epilogue: unnormalized O (fp16) + m,s per row ----
#pragma unroll
    for (int reg = 0; reg < 4; ++reg) {
        const int l = l0w + quad * 4 + reg;
        const size_t row = ((size_t)(half * B + bb) * NH + h) * L + l;
        f16* o = Opart + row * DH;
#pragma unroll
        for (int ns = 0; ns < 4; ++ns)
            o[ns * 16 + col] = (f16)O[ns][reg];
        if (col == 0) {
            Mpart[row] = mrow[reg];
            Spart[row] = Osum[reg];
        }
    }
}

// ---- combine two split-L partials; applies /(s*8), writes fp32 out ----
__global__ __launch_bounds__(256)
void combine_kernel(const f16* __restrict__ Opart, const float* __restrict__ Mpart,
                    const float* __restrict__ Spart, float* __restrict__ out) {
    const int gid = blockIdx.x * 256 + threadIdx.x;
    const int row = gid >> 3;                           // (bb*NH+h)*L + l
    const int dseg = (gid & 7) * 8;
    const int bb = row >> 14;
    const int rem = row & 16383;
    const int h = rem >> 11, l = rem & 2047;
    const int HSTRIDE = B * NH * L;

    const float m0 = Mpart[row], m1 = Mpart[row + HSTRIDE];
    const float s0 = Spart[row], s1 = Spart[row + HSTRIDE];
    const float m = fmaxf(m0, m1);
    const float e0 = __expf(m0 - m), e1 = __expf(m1 - m);
    const float inv = 1.0f / ((s0 * e0 + s1 * e1) * 8.0f);
    const float w0 = e0 * inv, w1 = e1 * inv;

    f16x8 o0 = *(const f16x8*)(Opart + (size_t)row * DH + dseg);
    f16x8 o1 = *(const f16x8*)(Opart + ((size_t)row + HSTRIDE) * DH + dseg);
    float* o = out + ((size_t)bb * L + l) * D + h * DH + dseg;
    float4 lo, hi;
    lo.x = (float)o0[0] * w0 + (float)o1[0] * w1;
    lo.y = (float)o0[1] * w0 + (float)o1[1] * w1;
    lo.z = (float)o0[2] * w0 + (float)o1[2] * w1;
    lo.w = (float)o0[3] * w0 + (float)o1[3] * w1;
    hi.x = (float)o0[4] * w0 + (float)o1[4] * w1;
    hi.y = (float)o0[5] * w0 + (float)o1[5] * w1;
    hi.z = (float)o0[6] * w0 + (float)o1[6] * w1;
    hi.w = (float)o0[7] * w0 + (float)o1[7] * w1;
    *(float4*)o = lo;
    *(float4*)(o + 4) = hi;
}

extern "C" void kernel_launch(void* const* d_in, const int* in_sizes, int n_in,
                              void* d_out, int out_size, void* d_ws, size_t ws_size,
                              hipStream_t stream) {
    const float* q  = (const float*)d_in[0];
    const float* k  = (const float*)d_in[1];
    const float* v  = (const float*)d_in[2];
    const float* Wq = (const float*)d_in[3];
    const float* Wk = (const float*)d_in[4];
    const float* Wv = (const float*)d_in[5];
    const float* E  = (const float*)d_in[6];
    float* out = (float*)d_out;

    const size_t plane = (size_t)B * NH * L * DH;
    f16* Qf  = (f16*)d_ws;
    f16* Kfp = Qf + plane;
    f16* Vtf = Kfp + plane;
    f16* Wt  = Vtf + plane;
    f16* Ef  = Wt + (size_t)3 * D * D;
    f16* Opart = Ef + (size_t)L * DH;
    float* Mpart = (float*)(Opart + 2 * plane);
    float* Spart = Mpart + (size_t)2 * B * NH * L;

    ecast_kernel<<<L * DH / 1024, 256, 0, stream>>>(E, Ef);
    wtrans_kernel<<<dim3(8, 8, 3), 256, 0, stream>>>(Wq, Wk, Wv, Wt);
    proj_gemm<<<dim3(64, 24), 256, 0, stream>>>(q, k, v, Wt, Qf, Kfp, Vtf);
    attn_kernel<<<dim3(L / 64, NH, B * 2), 256, 0, stream>>>(Qf, Kfp, Vtf, Ef,
                                                             Opart, Mpart, Spart);
    combine_kernel<<<(B * NH * L * DH / 8) / 256, 256, 0, stream>>>(Opart, Mpart, Spart, out);
}